// Round 5
// baseline (377.363 us; speedup 1.0000x reference)
//
#include <hip/hip_runtime.h>
#include <math.h>
#include <float.h>

#define BN 32
#define CH 3
#define HH 512
#define WW 512
#define NP 4
#define EPS 128
#define HALF 64
#define MARGIN 32

#define PATCH_ELEMS (BN * NP * CH * EPS * EPS)   // 6291456
#define NT 4096          // 64x64 grid of 8x8 tiles per map
#define TPR 64
#define NBLK 256
#define NTHR 512

// ws layout: [0,64) barrier counters | [64,1088) coords_ws (256 ints)
//            [4096, +512K) tvg | next 512K tigg
#define WS_COORDS 64
#define WS_TVG    4096
#define WS_TIGG   (4096 + BN * NT * 4)

__device__ __forceinline__ void grid_barrier(unsigned* cnt) {
    __syncthreads();
    if (threadIdx.x == 0) {
        __threadfence();   // release: make this block's global writes agent-visible
        __hip_atomic_fetch_add(cnt, 1u, __ATOMIC_ACQ_REL, __HIP_MEMORY_SCOPE_AGENT);
        while (__hip_atomic_load(cnt, __ATOMIC_ACQUIRE, __HIP_MEMORY_SCOPE_AGENT) < NBLK)
            __builtin_amdgcn_s_sleep(8);
        __threadfence();   // acquire side
    }
    __syncthreads();
}

__global__ __launch_bounds__(NTHR)
void fused_kernel(const float* __restrict__ images,
                  const float* __restrict__ umaps,
                  float* __restrict__ out,          // patches then coords
                  char* __restrict__ ws)
{
    const int tid  = threadIdx.x;
    const int lane = tid & 63;
    const int wave = tid >> 6;

    unsigned* cnt      = (unsigned*)ws;
    int*      coords_w = (int*)(ws + WS_COORDS);
    float*    tvg      = (float*)(ws + WS_TVG);
    int*      tigg     = (int*)(ws + WS_TIGG);
    float*    coords_out = out + PATCH_ELEMS;

    __shared__ float tv[NT];
    __shared__ int   ti[NT];
    __shared__ int   boxes[NP][4];
    __shared__ float rv[8];
    __shared__ int   ri[8];
    __shared__ int   cw[BN * NP * 2];

    // ================= Phase 1: per-tile argmax (1 tile/thread) ==========
    {
        const int g  = blockIdx.x * NTHR + tid;      // < BN*NT = 131072
        const int b  = g >> 12;
        const int t  = g & (NT - 1);
        const int tx = t & (TPR - 1), ty = t >> 6;
        const float* __restrict__ um = umaps + (size_t)b * HH * WW;
        const int x0 = tx << 3, y0 = ty << 3;

        float bv = -INFINITY; int bi = 0x7fffffff;
        #pragma unroll
        for (int r = 0; r < 8; ++r) {
            const int rowbase = (y0 + r) * WW + x0;
            const float4 a = *(const float4*)(um + rowbase);
            const float4 c = *(const float4*)(um + rowbase + 4);
            if (a.x > bv) { bv = a.x; bi = rowbase + 0; }
            if (a.y > bv) { bv = a.y; bi = rowbase + 1; }
            if (a.z > bv) { bv = a.z; bi = rowbase + 2; }
            if (a.w > bv) { bv = a.w; bi = rowbase + 3; }
            if (c.x > bv) { bv = c.x; bi = rowbase + 4; }
            if (c.y > bv) { bv = c.y; bi = rowbase + 5; }
            if (c.z > bv) { bv = c.z; bi = rowbase + 6; }
            if (c.w > bv) { bv = c.w; bi = rowbase + 7; }
        }
        tvg[g] = bv; tigg[g] = bi;
    }

    grid_barrier(&cnt[0]);

    // ================= Phase 2: greedy selection (blocks 0..31) ==========
    if (blockIdx.x < BN) {
        const int b = blockIdx.x;
        const float* __restrict__ um = umaps + (size_t)b * HH * WW;

        #pragma unroll
        for (int i = 0; i < 8; ++i) {
            const int t = tid + (i << 9);
            tv[t] = __hip_atomic_load(&tvg[b * NT + t], __ATOMIC_RELAXED, __HIP_MEMORY_SCOPE_AGENT);
            ti[t] = __hip_atomic_load(&tigg[b * NT + t], __ATOMIC_RELAXED, __HIP_MEMORY_SCOPE_AGENT);
        }
        if (tid < NP) {   // all boxes start empty => mask tests are inert
            boxes[tid][0] = 0; boxes[tid][1] = 0; boxes[tid][2] = 0; boxes[tid][3] = 0;
        }
        __syncthreads();

        for (int k = 0; k < NP; ++k) {
            // ---- block argmax over 4096 entries ----
            float bv = -INFINITY; int bi = 0x7fffffff;
            #pragma unroll
            for (int i = 0; i < 8; ++i) {
                const int t = tid + (i << 9);
                const float v = tv[t]; const int x = ti[t];
                if (v > bv || (v == bv && x < bi)) { bv = v; bi = x; }
            }
            #pragma unroll
            for (int off = 32; off > 0; off >>= 1) {
                float ov = __shfl_down(bv, off);
                int   oi = __shfl_down(bi, off);
                if (ov > bv || (ov == bv && oi < bi)) { bv = ov; bi = oi; }
            }
            if (lane == 0) { rv[wave] = bv; ri[wave] = bi; }
            __syncthreads();

            if (tid == 0) {
                bv = rv[0]; bi = ri[0];
                #pragma unroll
                for (int w = 1; w < 8; ++w)
                    if (rv[w] > bv || (rv[w] == bv && ri[w] < bi)) { bv = rv[w]; bi = ri[w]; }
                const int yc = bi >> 9, xc = bi & 511;
                int x1 = max(0, xc - HALF), x2 = min(WW, xc + HALF);
                int y1 = max(0, yc - HALF), y2 = min(HH, yc + HALF);
                if (x2 - x1 < EPS) { if (x1 == 0) x2 = EPS; else x1 = x2 - EPS; }
                if (y2 - y1 < EPS) { if (y1 == 0) y2 = EPS; else y1 = y2 - EPS; }
                boxes[k][0] = max(x1 - MARGIN, 0);
                boxes[k][1] = min(x2 + MARGIN, WW);
                boxes[k][2] = max(y1 - MARGIN, 0);
                boxes[k][3] = min(y2 + MARGIN, HH);

                const int o = (b * NP + k) * 4;
                coords_out[o + 0] = (float)x1;
                coords_out[o + 1] = (float)y1;
                coords_out[o + 2] = (float)x2;
                coords_out[o + 3] = (float)y2;
                coords_w[(b * NP + k) * 2 + 0] = x1;
                coords_w[(b * NP + k) * 2 + 1] = y1;
            }
            __syncthreads();

            if (k == NP - 1) break;

            // all 4 boxes -> 16 plain registers (no arrays, no scratch)
            const int b00 = boxes[0][0], b01 = boxes[0][1], b02 = boxes[0][2], b03 = boxes[0][3];
            const int b10 = boxes[1][0], b11 = boxes[1][1], b12 = boxes[1][2], b13 = boxes[1][3];
            const int b20 = boxes[2][0], b21 = boxes[2][1], b22 = boxes[2][2], b23 = boxes[2][3];
            const int b30 = boxes[3][0], b31 = boxes[3][1], b32 = boxes[3][2], b33 = boxes[3][3];
            const int ex1 = boxes[k][0], ex2 = boxes[k][1];
            const int ey1 = boxes[k][2], ey2 = boxes[k][3];

            #pragma unroll
            for (int i = 0; i < 8; ++i) {
                const int t  = tid + (i << 9);
                const int tx = t & (TPR - 1), ty = t >> 6;
                const int X1 = tx << 3, Y1 = ty << 3;
                const int X2 = X1 + 8,  Y2 = Y1 + 8;
                if (X1 >= ex2 || X2 <= ex1 || Y1 >= ey2 || Y2 <= ey1) continue;
                if (X1 >= ex1 && X2 <= ex2 && Y1 >= ey1 && Y2 <= ey2) {
                    tv[t] = -INFINITY; ti[t] = 0x7fffffff; continue;
                }
                float nv = -INFINITY; int ni = 0x7fffffff;
                for (int r = 0; r < 8; ++r) {
                    const int y = Y1 + r;
                    const int rowbase = y * WW + X1;
                    const float4 a = *(const float4*)(um + rowbase);
                    const float4 c = *(const float4*)(um + rowbase + 4);
                    const float vals[8] = {a.x, a.y, a.z, a.w, c.x, c.y, c.z, c.w};
                    #pragma unroll
                    for (int j = 0; j < 8; ++j) {
                        const int xe = X1 + j;
                        const bool m =
                            (y >= b03 ? false : (y >= b02 && xe >= b00 && xe < b01)) ||
                            (y >= b13 ? false : (y >= b12 && xe >= b10 && xe < b11)) ||
                            (y >= b23 ? false : (y >= b22 && xe >= b20 && xe < b21)) ||
                            (y >= b33 ? false : (y >= b32 && xe >= b30 && xe < b31));
                        if (!m && vals[j] > nv) { nv = vals[j]; ni = rowbase + j; }
                    }
                }
                tv[t] = nv; ti[t] = ni;
            }
            __syncthreads();
        }
    }

    grid_barrier(&cnt[1]);

    // ================= Phase 3: extract (all blocks) =====================
    // cache coords in LDS
    if (tid < BN * NP * 2)
        cw[tid] = __hip_atomic_load(&coords_w[tid], __ATOMIC_RELAXED, __HIP_MEMORY_SCOPE_AGENT);
    __syncthreads();

    float4* __restrict__ out4 = (float4*)out;
    #pragma unroll
    for (int it = 0; it < 12; ++it) {
        const int i4   = (it * NBLK + blockIdx.x) * NTHR + tid;   // < PATCH_ELEMS/4
        const int px0  = (i4 & 31) << 2;
        const int py   = (i4 >> 5) & 127;
        const int rest = i4 >> 12;           // b*NP*CH + n*CH + c  (< 384)
        const int c    = rest % CH;
        const int bn   = rest / CH;
        const int b    = bn >> 2;

        const int x1 = cw[bn * 2 + 0];
        const int y1 = cw[bn * 2 + 1];

        const float* __restrict__ src =
            images + (((size_t)b * CH + c) * HH + (y1 + py)) * WW + x1 + px0;
        out4[i4] = make_float4(src[0], src[1], src[2], src[3]);
    }
}

extern "C" void kernel_launch(void* const* d_in, const int* in_sizes, int n_in,
                              void* d_out, int out_size, void* d_ws, size_t ws_size,
                              hipStream_t stream) {
    const float* images = (const float*)d_in[0];
    const float* umaps  = (const float*)d_in[1];
    float* out          = (float*)d_out;

    // zero the grid-barrier counters (ws is poisoned 0xAA before every launch)
    hipMemsetAsync(d_ws, 0, 64, stream);
    fused_kernel<<<NBLK, NTHR, 0, stream>>>(images, umaps, out, (char*)d_ws);
}

// Round 6
// 274.912 us; speedup vs baseline: 1.3727x; 1.3727x over previous
//
#include <hip/hip_runtime.h>
#include <math.h>
#include <float.h>

#define BN 32
#define CH 3
#define HH 512
#define WW 512
#define NP 4
#define EPS 128
#define HALF 64
#define MARGIN 32

#define PATCH_ELEMS (BN * NP * CH * EPS * EPS)   // 6291456
#define NT 4096          // 64x64 grid of 8x8 tiles per map
#define TPR 64
#define NBLK 256
#define NTHR 512
#define F4_PER_MAP (NP * CH * EPS * EPS / 4)     // 49152
#define SLICES 8
#define F4_PER_SLICE (F4_PER_MAP / SLICES)       // 6144 = 12 * 512

// ws layout: [0,64) barrier counter | [1024, +512K) tvg | next 512K tigg
#define WS_TVG  1024
#define WS_TIGG (1024 + BN * NT * 4)

__global__ __launch_bounds__(NTHR)
void fused_kernel(const float* __restrict__ images,
                  const float* __restrict__ umaps,
                  float* __restrict__ out,          // patches then coords
                  char* __restrict__ ws)
{
    const int tid  = threadIdx.x;
    const int lane = tid & 63;
    const int wave = tid >> 6;

    unsigned* cnt   = (unsigned*)ws;
    float*    tvg   = (float*)(ws + WS_TVG);
    int*      tigg  = (int*)(ws + WS_TIGG);
    float*    coords_out = out + PATCH_ELEMS;

    __shared__ float tv[NT];
    __shared__ int   ti[NT];
    __shared__ int   boxes[NP][4];
    __shared__ float rv[8];
    __shared__ int   ri[8];
    __shared__ int   sx1[NP];
    __shared__ int   sy1[NP];

    // ================= Phase 1: per-tile argmax (1 tile/thread) ==========
    {
        const int g  = blockIdx.x * NTHR + tid;      // < BN*NT = 131072
        const int b  = g >> 12;
        const int t  = g & (NT - 1);
        const int tx = t & (TPR - 1), ty = t >> 6;
        const float* __restrict__ um = umaps + (size_t)b * HH * WW;
        const int x0 = tx << 3, y0 = ty << 3;

        float bv = -INFINITY; int bi = 0x7fffffff;
        #pragma unroll
        for (int r = 0; r < 8; ++r) {
            const int rowbase = (y0 + r) * WW + x0;
            const float4 a = *(const float4*)(um + rowbase);
            const float4 c = *(const float4*)(um + rowbase + 4);
            if (a.x > bv) { bv = a.x; bi = rowbase + 0; }
            if (a.y > bv) { bv = a.y; bi = rowbase + 1; }
            if (a.z > bv) { bv = a.z; bi = rowbase + 2; }
            if (a.w > bv) { bv = a.w; bi = rowbase + 3; }
            if (c.x > bv) { bv = c.x; bi = rowbase + 4; }
            if (c.y > bv) { bv = c.y; bi = rowbase + 5; }
            if (c.z > bv) { bv = c.z; bi = rowbase + 6; }
            if (c.w > bv) { bv = c.w; bi = rowbase + 7; }
        }
        tvg[g] = bv; tigg[g] = bi;
    }

    // ---- single grid barrier ----
    __syncthreads();
    if (tid == 0) {
        __threadfence();   // release this block's tile-summary writes
        __hip_atomic_fetch_add(cnt, 1u, __ATOMIC_ACQ_REL, __HIP_MEMORY_SCOPE_AGENT);
        while (__hip_atomic_load(cnt, __ATOMIC_ACQUIRE, __HIP_MEMORY_SCOPE_AGENT) < NBLK)
            __builtin_amdgcn_s_sleep(2);
        __threadfence();
    }
    __syncthreads();

    // ====== Phase 2: greedy selection, computed REDUNDANTLY per block ======
    // 8 blocks share each map; all compute identical coords from identical
    // tile summaries (deterministic compares), so no further sync is needed.
    const int b     = blockIdx.x & (BN - 1);
    const int slice = blockIdx.x >> 5;
    const float* __restrict__ um = umaps + (size_t)b * HH * WW;

    #pragma unroll
    for (int i = 0; i < 8; ++i) {
        const int t = tid + (i << 9);
        tv[t] = __hip_atomic_load(&tvg[b * NT + t], __ATOMIC_RELAXED, __HIP_MEMORY_SCOPE_AGENT);
        ti[t] = __hip_atomic_load(&tigg[b * NT + t], __ATOMIC_RELAXED, __HIP_MEMORY_SCOPE_AGENT);
    }
    if (tid < NP) {   // all boxes start empty => mask tests inert
        boxes[tid][0] = 0; boxes[tid][1] = 0; boxes[tid][2] = 0; boxes[tid][3] = 0;
    }
    __syncthreads();

    for (int k = 0; k < NP; ++k) {
        // ---- block argmax over 4096 entries ----
        float bv = -INFINITY; int bi = 0x7fffffff;
        #pragma unroll
        for (int i = 0; i < 8; ++i) {
            const int t = tid + (i << 9);
            const float v = tv[t]; const int x = ti[t];
            if (v > bv || (v == bv && x < bi)) { bv = v; bi = x; }
        }
        #pragma unroll
        for (int off = 32; off > 0; off >>= 1) {
            float ov = __shfl_down(bv, off);
            int   oi = __shfl_down(bi, off);
            if (ov > bv || (ov == bv && oi < bi)) { bv = ov; bi = oi; }
        }
        if (lane == 0) { rv[wave] = bv; ri[wave] = bi; }
        __syncthreads();

        if (tid == 0) {
            bv = rv[0]; bi = ri[0];
            #pragma unroll
            for (int w = 1; w < 8; ++w)
                if (rv[w] > bv || (rv[w] == bv && ri[w] < bi)) { bv = rv[w]; bi = ri[w]; }
            const int yc = bi >> 9, xc = bi & 511;
            int x1 = max(0, xc - HALF), x2 = min(WW, xc + HALF);
            int y1 = max(0, yc - HALF), y2 = min(HH, yc + HALF);
            if (x2 - x1 < EPS) { if (x1 == 0) x2 = EPS; else x1 = x2 - EPS; }
            if (y2 - y1 < EPS) { if (y1 == 0) y2 = EPS; else y1 = y2 - EPS; }
            boxes[k][0] = max(x1 - MARGIN, 0);
            boxes[k][1] = min(x2 + MARGIN, WW);
            boxes[k][2] = max(y1 - MARGIN, 0);
            boxes[k][3] = min(y2 + MARGIN, HH);
            sx1[k] = x1; sy1[k] = y1;

            if (slice == 0) {
                const int o = (b * NP + k) * 4;
                coords_out[o + 0] = (float)x1;
                coords_out[o + 1] = (float)y1;
                coords_out[o + 2] = (float)x2;
                coords_out[o + 3] = (float)y2;
            }
        }
        __syncthreads();

        if (k == NP - 1) break;

        // all 4 boxes -> plain registers (no arrays => no scratch)
        const int b00 = boxes[0][0], b01 = boxes[0][1], b02 = boxes[0][2], b03 = boxes[0][3];
        const int b10 = boxes[1][0], b11 = boxes[1][1], b12 = boxes[1][2], b13 = boxes[1][3];
        const int b20 = boxes[2][0], b21 = boxes[2][1], b22 = boxes[2][2], b23 = boxes[2][3];
        const int b30 = boxes[3][0], b31 = boxes[3][1], b32 = boxes[3][2], b33 = boxes[3][3];
        const int ex1 = boxes[k][0], ex2 = boxes[k][1];
        const int ey1 = boxes[k][2], ey2 = boxes[k][3];

        #pragma unroll
        for (int i = 0; i < 8; ++i) {
            const int t  = tid + (i << 9);
            const int tx = t & (TPR - 1), ty = t >> 6;
            const int X1 = tx << 3, Y1 = ty << 3;
            const int X2 = X1 + 8,  Y2 = Y1 + 8;
            if (X1 >= ex2 || X2 <= ex1 || Y1 >= ey2 || Y2 <= ey1) continue;
            if (X1 >= ex1 && X2 <= ex2 && Y1 >= ey1 && Y2 <= ey2) {
                tv[t] = -INFINITY; ti[t] = 0x7fffffff; continue;
            }
            float nv = -INFINITY; int ni = 0x7fffffff;
            for (int r = 0; r < 8; ++r) {
                const int y = Y1 + r;
                const int rowbase = y * WW + X1;
                const float4 a = *(const float4*)(um + rowbase);
                const float4 c = *(const float4*)(um + rowbase + 4);
                const float vals[8] = {a.x, a.y, a.z, a.w, c.x, c.y, c.z, c.w};
                #pragma unroll
                for (int j = 0; j < 8; ++j) {
                    const int xe = X1 + j;
                    const bool m =
                        (y >= b02 && y < b03 && xe >= b00 && xe < b01) ||
                        (y >= b12 && y < b13 && xe >= b10 && xe < b11) ||
                        (y >= b22 && y < b23 && xe >= b20 && xe < b21) ||
                        (y >= b32 && y < b33 && xe >= b30 && xe < b31);
                    if (!m && vals[j] > nv) { nv = vals[j]; ni = rowbase + j; }
                }
            }
            tv[t] = nv; ti[t] = ni;
        }
        __syncthreads();
    }

    // ================= Phase 3: extract own map's slice ==================
    float4* __restrict__ out4 = (float4*)out;
    #pragma unroll
    for (int it = 0; it < 12; ++it) {
        const int il  = slice * F4_PER_SLICE + it * NTHR + tid;  // within-map f4 idx
        const int nc  = il >> 12;            // (n,c) plane, 0..11
        const int n   = nc / 3;
        const int c   = nc - n * 3;
        const int py  = (il >> 5) & 127;
        const int px0 = (il & 31) << 2;

        const int x1 = sx1[n], y1 = sy1[n];
        const float* __restrict__ src =
            images + (((size_t)b * CH + c) * HH + (y1 + py)) * WW + x1 + px0;
        out4[b * F4_PER_MAP + il] = make_float4(src[0], src[1], src[2], src[3]);
    }
}

extern "C" void kernel_launch(void* const* d_in, const int* in_sizes, int n_in,
                              void* d_out, int out_size, void* d_ws, size_t ws_size,
                              hipStream_t stream) {
    const float* images = (const float*)d_in[0];
    const float* umaps  = (const float*)d_in[1];
    float* out          = (float*)d_out;

    // zero the grid-barrier counter (ws is poisoned 0xAA before every launch)
    hipMemsetAsync(d_ws, 0, 64, stream);
    fused_kernel<<<NBLK, NTHR, 0, stream>>>(images, umaps, out, (char*)d_ws);
}